// Round 2
// baseline (4760.003 us; speedup 1.0000x reference)
//
#include <hip/hip_runtime.h>
#include <math.h>

// B=32, R=16384, C=16, IC=16, OC=16, 3 routing iterations.
// x: (B,C,IC) fp32 [8192]; W: (R,C,OC,IC) fp32 [67108864 = 256 MB]; out: (B,C,OC) fp32.
//
// Algebra: b after iter2 = <u,v1>, after iter3 = <u,v1+v2>, so no logit array is
// needed -- both routing passes are the same kernel with a different v vector.

#define RT 16384

#define DOT16(w0,w1,w2,w3,y0,y1,y2,y3) \
  (w0.x*y0.x + w0.y*y0.y + w0.z*y0.z + w0.w*y0.w + \
   w1.x*y1.x + w1.y*y1.y + w1.z*y1.z + w1.w*y1.w + \
   w2.x*y2.x + w2.y*y2.y + w2.z*y2.z + w2.w*y2.w + \
   w3.x*y3.x + w3.y*y3.y + w3.z*y3.z + w3.w*y3.w)

// async global->LDS, 16 B per lane. LDS dest = wave-uniform base + lane*16.
__device__ __forceinline__ void gload_lds16(const void* g, void* l) {
  __builtin_amdgcn_global_load_lds(
      (const __attribute__((address_space(1))) unsigned int*)g,
      (__attribute__((address_space(3))) unsigned int*)l, 16, 0, 0);
}

__device__ __forceinline__ float rfl(float v) {
  return __uint_as_float(__builtin_amdgcn_readfirstlane(__float_as_uint(v)));
}

// ---------------------------------------------------------------------------
// K1: partial W-sums, NO atomics (old version: 1M atomicAdds onto 4096 floats
// = 256-way contention, ~240 us). part[p][cls4] (float4), p = r-part [0,256),
// each part covers 64 consecutive r. 1024 blocks x 256 thr, 64 loads/thread,
// fully coalesced (consecutive threads -> consecutive float4s).
// ---------------------------------------------------------------------------
__global__ __launch_bounds__(256) void k_wsum(const float4* __restrict__ W4,
                                              float4* __restrict__ part) {
    int g = blockIdx.x & 3;                        // cls4 group [0,4)
    int p = blockIdx.x >> 2;                       // r-part    [0,256)
    int cls4 = g * 256 + threadIdx.x;              // [0,1024)
    const float4* base = W4 + (size_t)p * 64 * 1024 + cls4;
    float4 acc = {0.f, 0.f, 0.f, 0.f};
    #pragma unroll 8
    for (int rr = 0; rr < 64; ++rr) {
        float4 w = base[(size_t)rr * 1024];
        acc.x += w.x; acc.y += w.y; acc.z += w.z; acc.w += w.w;
    }
    part[p * 1024 + cls4] = acc;
}

// k_wred: wsum[cls] = sum_p part[p][cls].  4096 threads, coalesced per p.
__global__ __launch_bounds__(256) void k_wred(const float* __restrict__ part,
                                              float* __restrict__ wsum) {
    int cls = blockIdx.x * 256 + threadIdx.x;      // [0,4096)
    float acc = 0.f;
    #pragma unroll 8
    for (int p = 0; p < 256; ++p) acc += part[p * 4096 + cls];
    wsum[cls] = acc;
}

// ---------------------------------------------------------------------------
// K2: s1 = (1/R) * wsum . x ;  v1 = squash(s1)  -> v1[b*256 + c*16 + o]
// ---------------------------------------------------------------------------
__global__ __launch_bounds__(256) void k_v1(const float* __restrict__ wsum,
                                            const float* __restrict__ x,
                                            float* __restrict__ v1) {
    int t = blockIdx.x * 256 + threadIdx.x;        // 0..8191
    int o = t & 15, c = (t >> 4) & 15, b = t >> 8;
    const float* xb = x + (b * 16 + c) * 16;
    const float* wr = wsum + (c * 16 + o) * 16;
    float s = 0.f;
    #pragma unroll
    for (int i = 0; i < 16; ++i) s += wr[i] * xb[i];
    s *= (1.0f / 16384.0f);
    float ns = s * s;
    #pragma unroll
    for (int d = 1; d < 16; d <<= 1) ns += __shfl_xor(ns, d);
    v1[t] = s * (sqrtf(ns) / (1.0f + ns));
}

// ---------------------------------------------------------------------------
// k_vsum: v2 = squash(E/Z); vsum = v1 + v2   (dot vector for pass 3)
// ---------------------------------------------------------------------------
__global__ __launch_bounds__(256) void k_vsum(const float* __restrict__ E,
                                              const float* __restrict__ Z,
                                              const float* __restrict__ v1,
                                              float* __restrict__ vsum) {
    int t = blockIdx.x * 256 + threadIdx.x;        // 0..8191
    float s = E[t] / Z[t >> 4];
    float ns = s * s;
    #pragma unroll
    for (int d = 1; d < 16; d <<= 1) ns += __shfl_xor(ns, d);
    vsum[t] = v1[t] + s * (sqrtf(ns) / (1.0f + ns));
}

// ---------------------------------------------------------------------------
// k_vout: final v = squash(E/Z) -> out
// ---------------------------------------------------------------------------
__global__ __launch_bounds__(256) void k_vout(const float* __restrict__ E,
                                              const float* __restrict__ Z,
                                              float* __restrict__ dst) {
    int t = blockIdx.x * 256 + threadIdx.x;        // 0..8191
    float s = E[t] / Z[t >> 4];
    float ns = s * s;
    #pragma unroll
    for (int d = 1; d < 16; d <<= 1) ns += __shfl_xor(ns, d);
    dst[t] = s * (sqrtf(ns) / (1.0f + ns));
}

// ---------------------------------------------------------------------------
// k_route: one routing pass.  For each (b,c,r):
//   u[o]  = sum_i W[r,c,o,i] * x[b,c,i]
//   e     = exp(sum_o u[o]*v[b,c,o])      (|L|<=~40, safe in fp32)
//   E[b,c,o] += e*u[o];  Z[b,c] += e
// Block 512 = 8 waves; wave wv owns b in {4wv..4wv+3}; lane = r within the
// 64-row chunk; 4 chunks per block.  SINGLE 64 KB LDS buffer -> 2 blocks/CU
// (prev: 128 KB dbuf -> 1 block/CU, Occupancy 22.5%, VALUBusy 35%, latency-
// bound).  Cross-block overlap replaces within-block prefetch: while one
// block drains vmcnt at its barrier, the co-resident block computes.
// ---------------------------------------------------------------------------
__global__ __launch_bounds__(512, 1) void k_route(const float* __restrict__ W,
                                                  const float* __restrict__ x,
                                                  const float* __restrict__ v,
                                                  float* __restrict__ E,
                                                  float* __restrict__ Z) {
    __shared__ float4 Wl[64 * 64];                 // 64 KB single buffer
    const int c = blockIdx.y;
    const int r0 = blockIdx.x * 256;
    const int tid = threadIdx.x;
    const int wv = __builtin_amdgcn_readfirstlane(tid >> 6);
    const int lane = tid & 63;

    const float4* W4c = (const float4*)W + c * 64; // + r*1024 + j

    // x rows for this wave's 4 b's (VGPR), v rows in SGPRs (wave-uniform)
    float4 xr[4][4];
    float vs[4][16];
    #pragma unroll
    for (int bl = 0; bl < 4; ++bl) {
        const float4* xb = (const float4*)(x + ((wv * 4 + bl) * 16 + c) * 16);
        const float*  vb = v + ((wv * 4 + bl) * 16 + c) * 16;
        xr[bl][0] = xb[0]; xr[bl][1] = xb[1]; xr[bl][2] = xb[2]; xr[bl][3] = xb[3];
        #pragma unroll
        for (int o = 0; o < 16; ++o) vs[bl][o] = rfl(vb[o]);
    }

    float accE[4][16];
    float accZ[4] = {0.f, 0.f, 0.f, 0.f};
    #pragma unroll
    for (int bl = 0; bl < 4; ++bl)
        #pragma unroll
        for (int o = 0; o < 16; ++o) accE[bl][o] = 0.f;

    for (int ch = 0; ch < 4; ++ch) {
        if (ch) __syncthreads();                   // readers done with buffer
        // stage chunk: wave wv stages rows {k*8+wv}; lane l -> slot rl*64+l,
        // global source pre-swizzled (float4 l^rl) so reads can XOR-deswizzle.
        #pragma unroll
        for (int k = 0; k < 8; ++k) {
            int rl = k * 8 + wv;
            gload_lds16(W4c + (size_t)(r0 + ch * 64 + rl) * 1024 + (lane ^ rl),
                        &Wl[rl * 64]);
        }
        __syncthreads();                           // vmcnt(0) drain: tile ready

        float u[4][16];
        #pragma unroll
        for (int o = 0; o < 16; ++o) {
            float4 w0 = Wl[lane * 64 + ((o * 4 + 0) ^ lane)];
            float4 w1 = Wl[lane * 64 + ((o * 4 + 1) ^ lane)];
            float4 w2 = Wl[lane * 64 + ((o * 4 + 2) ^ lane)];
            float4 w3 = Wl[lane * 64 + ((o * 4 + 3) ^ lane)];
            #pragma unroll
            for (int bl = 0; bl < 4; ++bl)
                u[bl][o] = DOT16(w0, w1, w2, w3,
                                 xr[bl][0], xr[bl][1], xr[bl][2], xr[bl][3]);
        }

        #pragma unroll
        for (int bl = 0; bl < 4; ++bl) {
            float Lv = 0.f;
            #pragma unroll
            for (int o = 0; o < 16; ++o) Lv += u[bl][o] * vs[bl][o];
            float e = __expf(Lv);
            accZ[bl] += e;
            #pragma unroll
            for (int o = 0; o < 16; ++o) accE[bl][o] += e * u[bl][o];
        }
    }

    // Butterfly-reduce the 64 accE values + 4 accZ over the 64 lanes.
    float va = 0.f;
    #pragma unroll
    for (int bl = 0; bl < 4; ++bl) {
        #pragma unroll
        for (int o = 0; o < 16; ++o) {
            float t = accE[bl][o];
            #pragma unroll
            for (int d = 1; d < 64; d <<= 1) t += __shfl_xor(t, d);
            if (lane == bl * 16 + o) va = t;
        }
    }
    float vz = 0.f;
    #pragma unroll
    for (int bl = 0; bl < 4; ++bl) {
        float t = accZ[bl];
        #pragma unroll
        for (int d = 1; d < 64; d <<= 1) t += __shfl_xor(t, d);
        if (lane == bl) vz = t;
    }
    int b = wv * 4 + (lane >> 4);
    atomicAdd(&E[b * 256 + c * 16 + (lane & 15)], va);
    if (lane < 4) atomicAdd(&Z[(wv * 4 + lane) * 16 + c], vz);
}

// ---------------------------------------------------------------------------
// launch
// ---------------------------------------------------------------------------
extern "C" void kernel_launch(void* const* d_in, const int* in_sizes, int n_in,
                              void* d_out, int out_size, void* d_ws, size_t ws_size,
                              hipStream_t stream) {
    const float* x = (const float*)d_in[0];        // 8192 floats
    const float* W = (const float*)d_in[1];        // 67108864 floats (256 MB)
    float* out = (float*)d_out;                    // 8192 floats
    float* ws = (float*)d_ws;

    float* wsum = ws + 0;          // 4096
    float* E2   = ws + 4096;       // 8192
    float* Z2   = ws + 12288;      // 512
    float* E3   = ws + 12800;      // 8192
    float* Z3   = ws + 20992;      // 512   (zeroed region ends at 21504)
    float* v1   = ws + 21504;      // 8192
    float* vsum = ws + 29696;      // 8192
    float* part = ws + 37888;      // 1048576 (4 MB): 256 x 1024 float4 partials

    hipMemsetAsync(ws, 0, 21504 * sizeof(float), stream);

    // iter 1: uniform softmax -> v1 from Wsum (W pass 1), atomic-free
    k_wsum<<<1024, 256, 0, stream>>>((const float4*)W, (float4*)part);
    k_wred<<<16, 256, 0, stream>>>(part, wsum);
    k_v1<<<32, 256, 0, stream>>>(wsum, x, v1);

    // iter 2: logits = <u, v1>  (W pass 2)
    k_route<<<dim3(64, 16), 512, 0, stream>>>(W, x, v1, E2, Z2);
    k_vsum<<<32, 256, 0, stream>>>(E2, Z2, v1, vsum);  // vsum = v1 + squash(E2/Z2)

    // iter 3: logits = <u, v1+v2>  (W pass 3)
    k_route<<<dim3(64, 16), 512, 0, stream>>>(W, x, vsum, E3, Z3);
    k_vout<<<32, 256, 0, stream>>>(E3, Z3, out);
}

// Round 3
// 1480.288 us; speedup vs baseline: 3.2156x; 3.2156x over previous
//
#include <hip/hip_runtime.h>
#include <math.h>

// B=32, R=16384, C=16, IC=16, OC=16, 3 routing iterations.
// x: (B,C,IC) fp32 [8192]; W: (R,C,OC,IC) fp32 [67108864 = 256 MB]; out: (B,C,OC) fp32.
//
// Algebra: b after iter2 = <u,v1>, after iter3 = <u,v1+v2>, so no logit array is
// needed -- both routing passes are the same kernel with a different v vector.

#define RT 16384

// async global->LDS, 4 B per lane. LDS dest = wave-uniform base + lane*4.
__device__ __forceinline__ void gload_lds4(const void* g, void* l) {
  __builtin_amdgcn_global_load_lds(
      (const __attribute__((address_space(1))) unsigned int*)g,
      (__attribute__((address_space(3))) unsigned int*)l, 4, 0, 0);
}

__device__ __forceinline__ float rfl(float v) {
  return __uint_as_float(__builtin_amdgcn_readfirstlane(__float_as_uint(v)));
}

// ---------------------------------------------------------------------------
// K1: partial W-sums, NO atomics. part[p][cls4] (float4), p = r-part [0,256),
// each part covers 64 consecutive r. Fully coalesced.
// ---------------------------------------------------------------------------
__global__ __launch_bounds__(256) void k_wsum(const float4* __restrict__ W4,
                                              float4* __restrict__ part) {
    int g = blockIdx.x & 3;                        // cls4 group [0,4)
    int p = blockIdx.x >> 2;                       // r-part    [0,256)
    int cls4 = g * 256 + threadIdx.x;              // [0,1024)
    const float4* base = W4 + (size_t)p * 64 * 1024 + cls4;
    float4 acc = {0.f, 0.f, 0.f, 0.f};
    #pragma unroll 8
    for (int rr = 0; rr < 64; ++rr) {
        float4 w = base[(size_t)rr * 1024];
        acc.x += w.x; acc.y += w.y; acc.z += w.z; acc.w += w.w;
    }
    part[p * 1024 + cls4] = acc;
}

// k_wred: wsum[cls] = sum_p part[p][cls].
__global__ __launch_bounds__(256) void k_wred(const float* __restrict__ part,
                                              float* __restrict__ wsum) {
    int cls = blockIdx.x * 256 + threadIdx.x;      // [0,4096)
    float acc = 0.f;
    #pragma unroll 8
    for (int p = 0; p < 256; ++p) acc += part[p * 4096 + cls];
    wsum[cls] = acc;
}

// ---------------------------------------------------------------------------
// K2: s1 = (1/R) * wsum . x ;  v1 = squash(s1)
// ---------------------------------------------------------------------------
__global__ __launch_bounds__(256) void k_v1(const float* __restrict__ wsum,
                                            const float* __restrict__ x,
                                            float* __restrict__ v1) {
    int t = blockIdx.x * 256 + threadIdx.x;        // 0..8191
    int o = t & 15, c = (t >> 4) & 15, b = t >> 8;
    const float* xb = x + (b * 16 + c) * 16;
    const float* wr = wsum + (c * 16 + o) * 16;
    float s = 0.f;
    #pragma unroll
    for (int i = 0; i < 16; ++i) s += wr[i] * xb[i];
    s *= (1.0f / 16384.0f);
    float ns = s * s;
    #pragma unroll
    for (int d = 1; d < 16; d <<= 1) ns += __shfl_xor(ns, d);
    v1[t] = s * (sqrtf(ns) / (1.0f + ns));
}

// k_vsum: v2 = squash(E/Z); vsum = v1 + v2
__global__ __launch_bounds__(256) void k_vsum(const float* __restrict__ E,
                                              const float* __restrict__ Z,
                                              const float* __restrict__ v1,
                                              float* __restrict__ vsum) {
    int t = blockIdx.x * 256 + threadIdx.x;
    float s = E[t] / Z[t >> 4];
    float ns = s * s;
    #pragma unroll
    for (int d = 1; d < 16; d <<= 1) ns += __shfl_xor(ns, d);
    vsum[t] = v1[t] + s * (sqrtf(ns) / (1.0f + ns));
}

// k_vout: final v = squash(E/Z) -> out
__global__ __launch_bounds__(256) void k_vout(const float* __restrict__ E,
                                              const float* __restrict__ Z,
                                              float* __restrict__ dst) {
    int t = blockIdx.x * 256 + threadIdx.x;
    float s = E[t] / Z[t >> 4];
    float ns = s * s;
    #pragma unroll
    for (int d = 1; d < 16; d <<= 1) ns += __shfl_xor(ns, d);
    dst[t] = s * (sqrtf(ns) / (1.0f + ns));
}

// ---------------------------------------------------------------------------
// k_route: one routing pass.
// Round-1 macro-structure (128 KB LDS double buffer, prefetch-then-compute,
// unrolled chunk loop -- measured 221 us/pass) with the LDS conflict fix:
//   LDS layout is DWORD-XOR swizzled: row r dword d lives at r*256 + (d^(r&31)).
//   For a fixed d, the 64 lanes (lane=row) hit all 32 banks, 2 lanes each
//   (different rows = 2-way aliasing, free). Old float4 layout: 8 lanes/quad =
//   4x over floor on 512 KB of LDS reads per 64 KB chunk -- the real reason
//   round-1 sat at 221 us (VALUBusy 35%, HBM 11%).
// Staging: global_load_lds size=4, linear LDS dest, pre-XOR'd global source.
// Register diet: x -> SGPR (readfirstlane, wave-uniform), v -> 2 KB LDS
// broadcast table (same-address reads are free), so no scratch spills
// (round-2 failure mode: WRITE_SIZE 3.9 GB of spill traffic).
// REV: pass 2 walks r backwards (k_wsum ends at high r; L3 ~ |W|).
// ---------------------------------------------------------------------------
template <int REV>
__global__ __launch_bounds__(512, 1) void k_route(const float* __restrict__ W,
                                                  const float* __restrict__ x,
                                                  const float* __restrict__ v,
                                                  float* __restrict__ E,
                                                  float* __restrict__ Z) {
    __shared__ float Wl[2 * 64 * 256];             // 128 KB double buffer
    __shared__ float Vl[512];                      // v broadcast table (2 KB)
    const int c = blockIdx.y;
    const int bx = REV ? (63 - (int)blockIdx.x) : (int)blockIdx.x;
    const int r0 = bx * 256;
    const int tid = threadIdx.x;
    const int wv = __builtin_amdgcn_readfirstlane(tid >> 6);
    const int lane = tid & 63;

    // v -> LDS broadcast table: Vl[b*16+o]
    {
        int b = tid >> 4, o = tid & 15;
        Vl[tid] = v[(b * 16 + c) * 16 + o];
    }

    // x -> SGPRs (wave-uniform per (b,c))
    float xs[4][16];
    #pragma unroll
    for (int bl = 0; bl < 4; ++bl) {
        const float* xb = x + ((wv * 4 + bl) * 16 + c) * 16;
        #pragma unroll
        for (int i = 0; i < 16; ++i) xs[bl][i] = rfl(xb[i]);
    }

    float accE[4][16];
    float accZ[4] = {0.f, 0.f, 0.f, 0.f};
    #pragma unroll
    for (int bl = 0; bl < 4; ++bl)
        #pragma unroll
        for (int o = 0; o < 16; ++o) accE[bl][o] = 0.f;

    // ---- stage chunk 0 (wave wv stages rows k*8+wv; 4 x 256B per row) ----
    #pragma unroll
    for (int k = 0; k < 8; ++k) {
        int rl = k * 8 + wv, rot = rl & 31;
        const float* src = W + ((size_t)(r0 + rl) * 16 + c) * 256;
        float* dst = &Wl[rl * 256];
        #pragma unroll
        for (int q = 0; q < 4; ++q)
            gload_lds4(src + q * 64 + (lane ^ rot), dst + q * 64);
    }
    __syncthreads();                               // drains vmcnt(0) + Vl writes

    const int Pdw = lane * 256 + (lane & 31);      // lane = row; XOR base

    #pragma unroll
    for (int ch = 0; ch < 4; ++ch) {
        if (ch < 3) {                              // prefetch next chunk
            #pragma unroll
            for (int k = 0; k < 8; ++k) {
                int rl = k * 8 + wv, rot = rl & 31;
                const float* src = W + ((size_t)(r0 + (ch + 1) * 64 + rl) * 16 + c) * 256;
                float* dst = &Wl[((ch + 1) & 1) * 16384 + rl * 256];
                #pragma unroll
                for (int q = 0; q < 4; ++q)
                    gload_lds4(src + q * 64 + (lane ^ rot), dst + q * 64);
            }
        }
        const float* Wb = Wl + (ch & 1) * 16384;

        float u[4][16];
        #pragma unroll
        for (int o = 0; o < 16; ++o) {
            float w[16];
            #pragma unroll
            for (int t = 0; t < 16; ++t) w[t] = Wb[Pdw ^ (o * 16 + t)];
            #pragma unroll
            for (int bl = 0; bl < 4; ++bl) {
                float s = 0.f;
                #pragma unroll
                for (int t = 0; t < 16; ++t) s += w[t] * xs[bl][t];
                u[bl][o] = s;
            }
        }

        #pragma unroll
        for (int bl = 0; bl < 4; ++bl) {
            const float* vb = &Vl[(wv * 4 + bl) * 16];   // broadcast reads
            float Lv = 0.f;
            #pragma unroll
            for (int o = 0; o < 16; ++o) Lv += u[bl][o] * vb[o];
            float e = __expf(Lv);
            accZ[bl] += e;
            #pragma unroll
            for (int o = 0; o < 16; ++o) accE[bl][o] += e * u[bl][o];
        }
        __syncthreads();                           // prefetch landed; buffers swap
    }

    // Butterfly-reduce the 64 accE values + 4 accZ over the 64 lanes.
    float va = 0.f;
    #pragma unroll
    for (int bl = 0; bl < 4; ++bl) {
        #pragma unroll
        for (int o = 0; o < 16; ++o) {
            float t = accE[bl][o];
            #pragma unroll
            for (int d = 1; d < 64; d <<= 1) t += __shfl_xor(t, d);
            if (lane == bl * 16 + o) va = t;
        }
    }
    float vz = 0.f;
    #pragma unroll
    for (int bl = 0; bl < 4; ++bl) {
        float t = accZ[bl];
        #pragma unroll
        for (int d = 1; d < 64; d <<= 1) t += __shfl_xor(t, d);
        if (lane == bl) vz = t;
    }
    int b = wv * 4 + (lane >> 4);
    atomicAdd(&E[b * 256 + c * 16 + (lane & 15)], va);
    if (lane < 4) atomicAdd(&Z[(wv * 4 + lane) * 16 + c], vz);
}

// ---------------------------------------------------------------------------
// launch
// ---------------------------------------------------------------------------
extern "C" void kernel_launch(void* const* d_in, const int* in_sizes, int n_in,
                              void* d_out, int out_size, void* d_ws, size_t ws_size,
                              hipStream_t stream) {
    const float* x = (const float*)d_in[0];        // 8192 floats
    const float* W = (const float*)d_in[1];        // 67108864 floats (256 MB)
    float* out = (float*)d_out;                    // 8192 floats
    float* ws = (float*)d_ws;

    float* wsum = ws + 0;          // 4096
    float* E2   = ws + 4096;       // 8192
    float* Z2   = ws + 12288;      // 512
    float* E3   = ws + 12800;      // 8192
    float* Z3   = ws + 20992;      // 512   (zeroed region ends at 21504)
    float* v1   = ws + 21504;      // 8192
    float* vsum = ws + 29696;      // 8192
    float* part = ws + 37888;      // 1048576 (4 MB): 256 x 1024 float4 partials

    hipMemsetAsync(ws, 0, 21504 * sizeof(float), stream);

    // iter 1: uniform softmax -> v1 from Wsum (W pass 1), atomic-free
    k_wsum<<<1024, 256, 0, stream>>>((const float4*)W, (float4*)part);
    k_wred<<<16, 256, 0, stream>>>(part, wsum);
    k_v1<<<32, 256, 0, stream>>>(wsum, x, v1);

    // iter 2: logits = <u, v1>  (W pass 2, reverse r for L3 reuse)
    k_route<1><<<dim3(64, 16), 512, 0, stream>>>(W, x, v1, E2, Z2);
    k_vsum<<<32, 256, 0, stream>>>(E2, Z2, v1, vsum);  // vsum = v1 + squash(E2/Z2)

    // iter 3: logits = <u, v1+v2>  (W pass 3, forward r)
    k_route<0><<<dim3(64, 16), 512, 0, stream>>>(W, x, vsum, E3, Z3);
    k_vout<<<32, 256, 0, stream>>>(E3, Z3, out);
}

// Round 4
// 694.104 us; speedup vs baseline: 6.8578x; 2.1327x over previous
//
#include <hip/hip_runtime.h>
#include <math.h>

// B=32, R=16384, C=16, IC=16, OC=16, 3 routing iterations.
// x: (B,C,IC) fp32 [8192]; W: (R,C,OC,IC) fp32 [67108864 = 256 MB]; out: (B,C,OC) fp32.
//
// Algebra: b after iter2 = <u,v1>, after iter3 = <u,v1+v2>, so no logit array is
// needed -- both routing passes are the same kernel with a different v vector.
//
// History: R1 (float4-XOR LDS, dbuf, gload_lds16) = 221 us/pass but VGPR_Count=128
// vs ~220 live regs -> silent scratch spills (WRITE_SIZE 43 MB > ~5 MB atomics).
// R2/R3 restructures amplified spilling (0.7-3.9 GB scratch traffic, VALUBusy 14%).
// This round: R1 k_route VERBATIM + amdgpu_waves_per_eu(2,2) -> 256-VGPR budget
// (8 waves x 256 = 2048 VGPRs = the CU pool; LDS already pins 1 block/CU).

#define RT 16384

#define DOT16(w0,w1,w2,w3,y0,y1,y2,y3) \
  (w0.x*y0.x + w0.y*y0.y + w0.z*y0.z + w0.w*y0.w + \
   w1.x*y1.x + w1.y*y1.y + w1.z*y1.z + w1.w*y1.w + \
   w2.x*y2.x + w2.y*y2.y + w2.z*y2.z + w2.w*y2.w + \
   w3.x*y3.x + w3.y*y3.y + w3.z*y3.z + w3.w*y3.w)

// async global->LDS, 16 B per lane. LDS dest = wave-uniform base + lane*16.
__device__ __forceinline__ void gload_lds16(const void* g, void* l) {
  __builtin_amdgcn_global_load_lds(
      (const __attribute__((address_space(1))) unsigned int*)g,
      (__attribute__((address_space(3))) unsigned int*)l, 16, 0, 0);
}

__device__ __forceinline__ float rfl(float v) {
  return __uint_as_float(__builtin_amdgcn_readfirstlane(__float_as_uint(v)));
}

// ---------------------------------------------------------------------------
// K1: partial W-sums, NO atomics. part[p][cls4] (float4), p = r-part [0,256),
// each part covers 64 consecutive r. Fully coalesced.
// ---------------------------------------------------------------------------
__global__ __launch_bounds__(256) void k_wsum(const float4* __restrict__ W4,
                                              float4* __restrict__ part) {
    int g = blockIdx.x & 3;                        // cls4 group [0,4)
    int p = blockIdx.x >> 2;                       // r-part    [0,256)
    int cls4 = g * 256 + threadIdx.x;              // [0,1024)
    const float4* base = W4 + (size_t)p * 64 * 1024 + cls4;
    float4 acc = {0.f, 0.f, 0.f, 0.f};
    #pragma unroll 8
    for (int rr = 0; rr < 64; ++rr) {
        float4 w = base[(size_t)rr * 1024];
        acc.x += w.x; acc.y += w.y; acc.z += w.z; acc.w += w.w;
    }
    part[p * 1024 + cls4] = acc;
}

// ---------------------------------------------------------------------------
// k_wred_v1: fused partial-reduction + v1.  Grid = 16 blocks (one per c).
// Phase 1: wsum_c[t] = sum_p part[p][c*256+t]  (coalesced), into LDS.
// Phase 2: v1[b,c,o] = squash_o((1/R) * wsum_c[o,:] . x[b,c,:]).
// ---------------------------------------------------------------------------
__global__ __launch_bounds__(256) void k_wred_v1(const float* __restrict__ part,
                                                 const float* __restrict__ x,
                                                 float* __restrict__ v1) {
    __shared__ float ws[256];
    int c = blockIdx.x, t = threadIdx.x;
    float acc = 0.f;
    #pragma unroll 8
    for (int p = 0; p < 256; ++p) acc += part[p * 4096 + c * 256 + t];
    ws[t] = acc;
    __syncthreads();
    int o = t & 15;
    #pragma unroll
    for (int bb = 0; bb < 2; ++bb) {
        int b = (t >> 4) + bb * 16;
        const float* xb = x + (b * 16 + c) * 16;
        float s = 0.f;
        #pragma unroll
        for (int i = 0; i < 16; ++i) s += ws[o * 16 + i] * xb[i];
        s *= (1.0f / 16384.0f);
        float ns = s * s;
        #pragma unroll
        for (int d = 1; d < 16; d <<= 1) ns += __shfl_xor(ns, d);
        v1[b * 256 + c * 16 + o] = s * (sqrtf(ns) / (1.0f + ns));
    }
}

// k_vsum: v2 = squash(E/Z); vsum = v1 + v2
__global__ __launch_bounds__(256) void k_vsum(const float* __restrict__ E,
                                              const float* __restrict__ Z,
                                              const float* __restrict__ v1,
                                              float* __restrict__ vsum) {
    int t = blockIdx.x * 256 + threadIdx.x;
    float s = E[t] / Z[t >> 4];
    float ns = s * s;
    #pragma unroll
    for (int d = 1; d < 16; d <<= 1) ns += __shfl_xor(ns, d);
    vsum[t] = v1[t] + s * (sqrtf(ns) / (1.0f + ns));
}

// k_vout: final v = squash(E/Z) -> out
__global__ __launch_bounds__(256) void k_vout(const float* __restrict__ E,
                                              const float* __restrict__ Z,
                                              float* __restrict__ dst) {
    int t = blockIdx.x * 256 + threadIdx.x;
    float s = E[t] / Z[t >> 4];
    float ns = s * s;
    #pragma unroll
    for (int d = 1; d < 16; d <<= 1) ns += __shfl_xor(ns, d);
    dst[t] = s * (sqrtf(ns) / (1.0f + ns));
}

// ---------------------------------------------------------------------------
// k_route: one routing pass (R1 structure + 256-VGPR budget).
//   u[o] = sum_i W[r,c,o,i]*x[b,c,i];  e = exp(<u,v>);  E += e*u;  Z += e.
// Block 512 = 8 waves; wave wv owns b in {4wv..4wv+3}; lane = r within the
// 64-row chunk; 4 chunks, 128 KB LDS double buffer, prefetch-then-compute.
// LDS float4-XOR swizzle: slot rl*64+l holds row rl's float4 (l^rl); within
// every 8-lane group the bank-quads ((col)^lane)&7 are distinct -> b128 reads
// at the 8-cycle floor.  x in VGPRs, v in SGPRs (wave-uniform, readfirstlane).
// amdgpu_waves_per_eu(2,2): 2 waves/SIMD target -> 256 VGPR budget -> the
// ~220-reg live set fits with ZERO scratch spills (the R1-R3 hidden cost).
// REV: pass 2 walks r backwards (k_wsum ends at high r; L3 ~ |W|).
// ---------------------------------------------------------------------------
template <int REV>
__global__ __launch_bounds__(512)
__attribute__((amdgpu_waves_per_eu(2, 2)))
void k_route(const float* __restrict__ W,
             const float* __restrict__ x,
             const float* __restrict__ v,
             float* __restrict__ E,
             float* __restrict__ Z) {
    __shared__ float4 Wl[2][64 * 64];              // 128 KB double buffer
    const int c = blockIdx.y;
    const int bx = REV ? (63 - (int)blockIdx.x) : (int)blockIdx.x;
    const int r0 = bx * 256;
    const int tid = threadIdx.x;
    const int wv = __builtin_amdgcn_readfirstlane(tid >> 6);
    const int lane = tid & 63;

    const float4* W4c = (const float4*)W + c * 64; // + r*1024 + j

    // x rows for this wave's 4 b's (VGPR), v rows in SGPRs (wave-uniform)
    float4 xr[4][4];
    float vs[4][16];
    #pragma unroll
    for (int bl = 0; bl < 4; ++bl) {
        const float4* xb = (const float4*)(x + ((wv * 4 + bl) * 16 + c) * 16);
        const float*  vb = v + ((wv * 4 + bl) * 16 + c) * 16;
        xr[bl][0] = xb[0]; xr[bl][1] = xb[1]; xr[bl][2] = xb[2]; xr[bl][3] = xb[3];
        #pragma unroll
        for (int o = 0; o < 16; ++o) vs[bl][o] = rfl(vb[o]);
    }

    float accE[4][16];
    float accZ[4] = {0.f, 0.f, 0.f, 0.f};
    #pragma unroll
    for (int bl = 0; bl < 4; ++bl)
        #pragma unroll
        for (int o = 0; o < 16; ++o) accE[bl][o] = 0.f;

    // stage chunk 0: wave wv stages rows {k*8+wv}; lane l writes slot rl*64+l,
    // so the global source is pre-swizzled: float4 (l ^ rl) of the row.
    #pragma unroll
    for (int k = 0; k < 8; ++k) {
        int rl = k * 8 + wv;
        gload_lds16(W4c + (size_t)(r0 + rl) * 1024 + (lane ^ rl), &Wl[0][rl * 64]);
    }
    __syncthreads();                               // drains vmcnt(0)

    #pragma unroll
    for (int ch = 0; ch < 4; ++ch) {
        if (ch < 3) {                              // issue next chunk's loads first
            #pragma unroll
            for (int k = 0; k < 8; ++k) {
                int rl = k * 8 + wv;
                gload_lds16(W4c + (size_t)(r0 + (ch + 1) * 64 + rl) * 1024 + (lane ^ rl),
                            &Wl[(ch + 1) & 1][rl * 64]);
            }
        }
        const float4* Wb = Wl[ch & 1];

        float u[4][16];
        #pragma unroll
        for (int o = 0; o < 16; ++o) {
            float4 w0 = Wb[lane * 64 + ((o * 4 + 0) ^ lane)];
            float4 w1 = Wb[lane * 64 + ((o * 4 + 1) ^ lane)];
            float4 w2 = Wb[lane * 64 + ((o * 4 + 2) ^ lane)];
            float4 w3 = Wb[lane * 64 + ((o * 4 + 3) ^ lane)];
            #pragma unroll
            for (int bl = 0; bl < 4; ++bl)
                u[bl][o] = DOT16(w0, w1, w2, w3,
                                 xr[bl][0], xr[bl][1], xr[bl][2], xr[bl][3]);
        }

        #pragma unroll
        for (int bl = 0; bl < 4; ++bl) {
            float Lv = 0.f;
            #pragma unroll
            for (int o = 0; o < 16; ++o) Lv += u[bl][o] * vs[bl][o];
            float e = __expf(Lv);
            accZ[bl] += e;
            #pragma unroll
            for (int o = 0; o < 16; ++o) accE[bl][o] += e * u[bl][o];
        }
        __syncthreads();   // barrier + vmcnt(0) drain of loads issued pre-compute
    }

    // Butterfly-reduce the 64 accE values + 4 accZ over the 64 lanes.
    float va = 0.f;
    #pragma unroll
    for (int bl = 0; bl < 4; ++bl) {
        #pragma unroll
        for (int o = 0; o < 16; ++o) {
            float t = accE[bl][o];
            #pragma unroll
            for (int d = 1; d < 64; d <<= 1) t += __shfl_xor(t, d);
            if (lane == bl * 16 + o) va = t;
        }
    }
    float vz = 0.f;
    #pragma unroll
    for (int bl = 0; bl < 4; ++bl) {
        float t = accZ[bl];
        #pragma unroll
        for (int d = 1; d < 64; d <<= 1) t += __shfl_xor(t, d);
        if (lane == bl) vz = t;
    }
    int b = wv * 4 + (lane >> 4);
    atomicAdd(&E[b * 256 + c * 16 + (lane & 15)], va);
    if (lane < 4) atomicAdd(&Z[(wv * 4 + lane) * 16 + c], vz);
}

// ---------------------------------------------------------------------------
// launch
// ---------------------------------------------------------------------------
extern "C" void kernel_launch(void* const* d_in, const int* in_sizes, int n_in,
                              void* d_out, int out_size, void* d_ws, size_t ws_size,
                              hipStream_t stream) {
    const float* x = (const float*)d_in[0];        // 8192 floats
    const float* W = (const float*)d_in[1];        // 67108864 floats (256 MB)
    float* out = (float*)d_out;                    // 8192 floats
    float* ws = (float*)d_ws;

    float* E2   = ws + 4096;       // 8192
    float* Z2   = ws + 12288;      // 512
    float* E3   = ws + 12800;      // 8192
    float* Z3   = ws + 20992;      // 512   (zeroed region ends at 21504)
    float* v1   = ws + 21504;      // 8192
    float* vsum = ws + 29696;      // 8192
    float* part = ws + 37888;      // 1048576 (4 MB): 256 x 1024 float4 partials

    hipMemsetAsync(ws, 0, 21504 * sizeof(float), stream);

    // iter 1: uniform softmax -> v1 from Wsum (W pass 1), atomic-free
    k_wsum<<<1024, 256, 0, stream>>>((const float4*)W, (float4*)part);
    k_wred_v1<<<16, 256, 0, stream>>>(part, x, v1);

    // iter 2: logits = <u, v1>  (W pass 2, reverse r for L3 reuse)
    k_route<1><<<dim3(64, 16), 512, 0, stream>>>(W, x, v1, E2, Z2);
    k_vsum<<<32, 256, 0, stream>>>(E2, Z2, v1, vsum);  // vsum = v1 + squash(E2/Z2)

    // iter 3: logits = <u, v1+v2>  (W pass 3, forward r)
    k_route<0><<<dim3(64, 16), 512, 0, stream>>>(W, x, vsum, E3, Z3);
    k_vout<<<32, 256, 0, stream>>>(E3, Z3, out);
}